// Round 1
// baseline (89.993 us; speedup 1.0000x reference)
//
#include <hip/hip_runtime.h>
#include <math.h>

// Quanvolution: x[8192,1,32,32] f32, weights[1,8] f32 -> out[8192,1024] f32
// One block per image, one thread per 4x4 patch (stride 2 over zero-padded 34x34).
// Circuit: RY(w[q]) on q=0..3, CNOT ring, RY(w[4+q]) folded into the measurement:
//   <Z_w> = cos(th_w) * Zbar_w - sin(th_w) * Xbar_w
// with Zbar/Xbar computed on the post-CNOT state. Normalization uses T = sum(st^2)
// (circuit is orthogonal, so T == ||v||^2 up to rounding).

#define TS 34  // LDS tile row stride (words); 34x34 zero-padded tile

// RY on qubit with bit-mask M (wire 0 = MSB = mask 8), half-angle cos C / sin S.
#define RY(M, C, S)                                                    \
    {                                                                  \
        _Pragma("unroll") for (int k = 0; k < 16; ++k) {               \
            if ((k & (M)) == 0) {                                      \
                float a0 = st[k], a1 = st[k | (M)];                    \
                st[k]       = (C) * a0 - (S) * a1;                     \
                st[k | (M)] = (S) * a0 + (C) * a1;                     \
            }                                                          \
        }                                                              \
    }

// CNOT(control mask MC, target mask MT): swap st[k] <-> st[k|MT] where control set.
#define CNOT(MC, MT)                                                   \
    {                                                                  \
        _Pragma("unroll") for (int k = 0; k < 16; ++k) {               \
            if ((k & (MC)) != 0 && (k & (MT)) == 0) {                  \
                float t = st[k];                                       \
                st[k] = st[k | (MT)];                                  \
                st[k | (MT)] = t;                                      \
            }                                                          \
        }                                                              \
    }

// Measurement for wire with mask M, full-angle cos CF / sin SF -> OUTV
#define MEAS(M, CF, SF, OUTV)                                          \
    {                                                                  \
        float A = 0.f, X = 0.f;                                        \
        _Pragma("unroll") for (int k = 0; k < 16; ++k) {               \
            if ((k & (M)) == 0) {                                      \
                A += q[k | (M)];                                       \
                X = fmaf(st[k], st[k | (M)], X);                       \
            }                                                          \
        }                                                              \
        float Zb = T - 2.0f * A;                                       \
        OUTV = ((CF) * Zb - (SF) * (2.0f * X)) * inv;                  \
    }

__global__ __launch_bounds__(256) void quanv_kernel(
    const float* __restrict__ x, const float* __restrict__ w,
    float* __restrict__ out)
{
    __shared__ float tile[34 * TS];
    __shared__ float trig[16];

    const int tid = threadIdx.x;
    const int b = blockIdx.x;

    // Per-block trig: trig[0..3]=cos(w/2), [4..7]=sin(w/2) (layer-1 half angles),
    // [8..11]=cos(w4..7), [12..15]=sin(w4..7) (folded layer-2 full angles).
    if (tid < 4) {
        float t = w[tid] * 0.5f;
        trig[tid]     = cosf(t);
        trig[4 + tid] = sinf(t);
    } else if (tid < 8) {
        float t = w[tid];
        trig[4 + tid] = cosf(t);  // -> trig[8..11]
        trig[8 + tid] = sinf(t);  // -> trig[12..15]
    }

    // Stage image (1024 f32) into zero-padded LDS tile.
    const float4 xin = *(const float4*)(x + (size_t)b * 1024 + (tid << 2));
    {
        int row = tid >> 3, col = (tid & 7) << 2;
        float* dst = &tile[row * TS + col];
        *(float2*)(dst)     = make_float2(xin.x, xin.y);
        *(float2*)(dst + 2) = make_float2(xin.z, xin.w);
    }
    // Zero the pad: rows 32..33 (68 contiguous words) + cols 32..33 of rows 0..31.
    if (tid < 68) {
        tile[32 * TS + tid] = 0.f;
    } else if (tid < 132) {
        int k = tid - 68;
        tile[(k >> 1) * TS + 32 + (k & 1)] = 0.f;
    }
    __syncthreads();

    // Gather this thread's 4x4 patch (row-major -> state index k = dr*4+dc).
    const int py = tid >> 4, px = tid & 15;
    const float* pp = &tile[(py << 1) * TS + (px << 1)];
    float st[16];
#pragma unroll
    for (int dr = 0; dr < 4; ++dr) {
        float2 u0 = *(const float2*)(pp + dr * TS);
        float2 u1 = *(const float2*)(pp + dr * TS + 2);
        st[dr * 4 + 0] = u0.x;
        st[dr * 4 + 1] = u0.y;
        st[dr * 4 + 2] = u1.x;
        st[dr * 4 + 3] = u1.y;
    }

    const float c0 = trig[0], c1 = trig[1], c2 = trig[2], c3 = trig[3];
    const float s0 = trig[4], s1 = trig[5], s2 = trig[6], s3 = trig[7];
    const float cf0 = trig[8],  cf1 = trig[9],  cf2 = trig[10], cf3 = trig[11];
    const float sf0 = trig[12], sf1 = trig[13], sf2 = trig[14], sf3 = trig[15];

    // Layer 1: RY on qubits 0..3 (masks 8,4,2,1).
    RY(8, c0, s0)
    RY(4, c1, s1)
    RY(2, c2, s2)
    RY(1, c3, s3)

    // CNOT ring: (0,1),(1,2),(2,3),(3,0).
    CNOT(8, 4)
    CNOT(4, 2)
    CNOT(2, 1)
    CNOT(1, 8)

    // Probabilities and norm (orthogonal circuit => T == ||v||^2 up to rounding).
    float q[16];
#pragma unroll
    for (int k = 0; k < 16; ++k) q[k] = st[k] * st[k];
    float T = ((q[0] + q[1]) + (q[2] + q[3])) + ((q[4] + q[5]) + (q[6] + q[7])) +
              (((q[8] + q[9]) + (q[10] + q[11])) + ((q[12] + q[13]) + (q[14] + q[15])));
    float inv = 1.0f / T;

    float e0, e1, e2, e3;
    MEAS(8, cf0, sf0, e0)
    MEAS(4, cf1, sf1, e1)
    MEAS(2, cf2, sf2, e2)
    MEAS(1, cf3, sf3, e3)

    // out[b, tid*4 + w] -- coalesced float4 store.
    *(float4*)(out + (size_t)b * 1024 + (tid << 2)) = make_float4(e0, e1, e2, e3);
}

extern "C" void kernel_launch(void* const* d_in, const int* in_sizes, int n_in,
                              void* d_out, int out_size, void* d_ws, size_t ws_size,
                              hipStream_t stream) {
    const float* x = (const float*)d_in[0];
    const float* w = (const float*)d_in[1];
    float* out = (float*)d_out;
    const int B = in_sizes[0] >> 10;  // 8192 images, 1024 px each
    quanv_kernel<<<B, 256, 0, stream>>>(x, w, out);
}